// Round 10
// baseline (727.560 us; speedup 1.0000x reference)
//
#include <hip/hip_runtime.h>
#include <hip/hip_bf16.h>
#include <math.h>

// Problem constants
#define NLAB 9
#define NL   2
#define DI   768
#define DM   1536
#define DS   16
#define KC   4
#define DD   96
#define BB   2
#define SS   2048
#define TT   (BB*SS)
#define EPSF 1e-6f

// chunked scan config
#define NCH  64
#define CL   (SS/NCH)   // 32

// skinny fused projection width: 16 (B) + 16 (C) + 96 (dd1)
#define NW   128
// split-K factor for the skinny GEMM (K=DM=1536 -> 8 x 192)
#define KS   8
#define KSL  (DM/KS)    // 192

typedef __attribute__((ext_vector_type(4))) float f32x4;
typedef __attribute__((ext_vector_type(8))) short bf16x8;
typedef __attribute__((ext_vector_type(4))) unsigned short us4;
typedef __attribute__((ext_vector_type(8))) unsigned short us8;

__device__ __forceinline__ float siluf(float x) { return x / (1.f + __expf(-x)); }
__device__ __forceinline__ float softplusf(float x) { return x > 15.f ? x : log1pf(__expf(x)); }

// f32 -> bf16 (RNE, finite inputs)
__device__ __forceinline__ unsigned short f2bf(float f) {
    unsigned u = __float_as_uint(f);
    return (unsigned short)((u + 0x7fffu + ((u >> 16) & 1u)) >> 16);
}
__device__ __forceinline__ float bf2f(unsigned short s) {
    return __uint_as_float((unsigned)s << 16);
}

// XCD-aware tile map: HW round-robins flat block id across 8 XCDs (flat&7).
// Square per-XCD regions so the working set fits the 4 MiB per-XCD L2.
__device__ __forceinline__ void xcd_map(int gx, int gy, int bx, int by,
                                        int& bmt, int& bnt)
{
    int flat = by * gx + bx;
    if ((gx & 1) == 0 && (gy & 3) == 0) {
        int halfx = gx >> 1, quarty = gy >> 2;
        int xcd = flat & 7, local = flat >> 3;
        bnt = (xcd & 1) * halfx + local % halfx;
        bmt = (xcd >> 1) * quarty + local / halfx;
    } else { bmt = by; bnt = bx; }
}

__global__ void f32_to_bf16(const float* __restrict__ src,
                            unsigned short* __restrict__ dst, int n)
{
    int i = (blockIdx.x * 256 + threadIdx.x) * 8;
    if (i >= n) return;
    float4 a = *(const float4*)(src + i);
    float4 b = *(const float4*)(src + i + 4);
    union { unsigned short s[8]; uint4 v; } o;
    o.s[0] = f2bf(a.x); o.s[1] = f2bf(a.y); o.s[2] = f2bf(a.z); o.s[3] = f2bf(a.w);
    o.s[4] = f2bf(b.x); o.s[5] = f2bf(b.y); o.s[6] = f2bf(b.z); o.s[7] = f2bf(b.w);
    *(uint4*)(dst + i) = o.v;
}

// x[t,:] = emb[ids[t],:] * mask[t]
__global__ void embed_kernel(const int* __restrict__ ids, const int* __restrict__ mask,
                             const float* __restrict__ emb, float* __restrict__ x)
{
    int t = blockIdx.x;
    int i = threadIdx.x;
    float m = (float)mask[t];
    int id = ids[t];
    float4 v = ((const float4*)(emb + (size_t)id * DI))[i];
    v.x *= m; v.y *= m; v.z *= m; v.w *= m;
    ((float4*)(x + (size_t)t * DI))[i] = v;
}

// h16[t,:] = bf16( x[t,:] * rsqrt(mean(x^2)+eps) * w )  — float4-vectorized (G13)
__global__ __launch_bounds__(192) void rmsnorm_kernel(
    const float* __restrict__ x, const float* __restrict__ w,
    unsigned short* __restrict__ h)
{
    __shared__ float red[3];
    int t = blockIdx.x;
    float4 v = ((const float4*)(x + (size_t)t * DI))[threadIdx.x];
    float ss = v.x * v.x + v.y * v.y + v.z * v.z + v.w * v.w;
    #pragma unroll
    for (int m = 1; m < 64; m <<= 1) ss += __shfl_xor(ss, m, 64);
    if ((threadIdx.x & 63) == 0) red[threadIdx.x >> 6] = ss;
    __syncthreads();
    float scale = rsqrtf((red[0] + red[1] + red[2]) * (1.f / DI) + EPSF);
    float4 wv = ((const float4*)w)[threadIdx.x];
    us4 o = { f2bf(v.x * scale * wv.x), f2bf(v.y * scale * wv.y),
              f2bf(v.z * scale * wv.z), f2bf(v.w * scale * wv.w) };
    *(us4*)(h + (size_t)t * DI + threadIdx.x * 4) = o;
}

// ---- 128x128 bf16 MFMA GEMM: 3-buffer pipeline, counted vmcnt (validated) ----
#define STAGE_TILE(AS, BS, KT) do {                                                           \
    _Pragma("unroll")                                                                         \
    for (int it = 0; it < 2; ++it) {                                                          \
        int rbase = it * 64 + wave * 16;                                                      \
        int row = rbase + (lane >> 2);                                                        \
        int c8 = (((lane & 3) ^ ((lane >> 3) & 3)) * 8);                                      \
        __builtin_amdgcn_global_load_lds(                                                     \
            (const __attribute__((address_space(1))) unsigned int*)(Arow + (size_t)row * lda + (KT) + c8), \
            (__attribute__((address_space(3))) unsigned int*)((AS) + rbase * 32), 16, 0, 0);  \
        __builtin_amdgcn_global_load_lds(                                                     \
            (const __attribute__((address_space(1))) unsigned int*)(Brow + (size_t)row * ldb + (KT) + c8), \
            (__attribute__((address_space(3))) unsigned int*)((BS) + rbase * 32), 16, 0, 0);  \
    } } while (0)

#define COMPUTE_TILE(AS, BS) do {                                                             \
    bf16x8 af[4], bfr[4];                                                                     \
    const int khs = (kh ^ ((lr >> 1) & 3)) * 8;                                               \
    _Pragma("unroll")                                                                         \
    for (int i = 0; i < 4; ++i)                                                               \
        af[i] = *(const bf16x8*)&(AS)[(wm + i * 16 + lr) * 32 + khs];                         \
    _Pragma("unroll")                                                                         \
    for (int j = 0; j < 4; ++j)                                                               \
        bfr[j] = *(const bf16x8*)&(BS)[(wn + j * 16 + lr) * 32 + khs];                        \
    _Pragma("unroll")                                                                         \
    for (int i = 0; i < 4; ++i)                                                               \
        _Pragma("unroll")                                                                     \
        for (int j = 0; j < 4; ++j)                                                           \
            acc[i][j] = __builtin_amdgcn_mfma_f32_16x16x32_bf16(af[i], bfr[j], acc[i][j], 0, 0, 0); \
    } while (0)

#define WAIT_BAR(T, NT) do {                                                                  \
    if ((T) + 1 < (NT)) asm volatile("s_waitcnt vmcnt(4)" ::: "memory");                      \
    else                asm volatile("s_waitcnt vmcnt(0)" ::: "memory");                      \
    __builtin_amdgcn_s_barrier();                                                             \
} while (0)

// out16: when 1, C is written as bf16 (ushort*), act/bias/Rres still applied in f32.
__global__ __launch_bounds__(256) void gemm_bf16(
    const unsigned short* __restrict__ A, const unsigned short* __restrict__ B,
    const float* __restrict__ Rres, const float* __restrict__ bias,
    float* __restrict__ C, int M, int N, int K,
    int lda, int ldb, int ldc, int act, int out16)
{
    __shared__ unsigned short As0[128 * 32];
    __shared__ unsigned short Bs0[128 * 32];
    __shared__ unsigned short As1[128 * 32];
    __shared__ unsigned short Bs1[128 * 32];
    __shared__ unsigned short As2[128 * 32];
    __shared__ unsigned short Bs2[128 * 32];
    const int tid = threadIdx.x;
    const int wave = tid >> 6, lane = tid & 63;

    int bmt, bnt;
    xcd_map(gridDim.x, gridDim.y, blockIdx.x, blockIdx.y, bmt, bnt);
    const int bm = bmt * 128, bn = bnt * 128;

    const int wm = (wave >> 1) * 64, wn = (wave & 1) * 64;
    const int lr = lane & 15, kh = lane >> 4;

    f32x4 acc[4][4] = {};

    const unsigned short* Arow = A + (size_t)bm * lda;
    const unsigned short* Brow = B + (size_t)bn * ldb;

    const int nt = K >> 5;
    STAGE_TILE(As0, Bs0, 0);
    if (nt > 1) STAGE_TILE(As1, Bs1, 32);

    int t = 0;
    while (true) {
        WAIT_BAR(t, nt);
        if (t + 2 < nt) STAGE_TILE(As2, Bs2, (t + 2) * 32);
        COMPUTE_TILE(As0, Bs0);
        if (++t == nt) break;
        WAIT_BAR(t, nt);
        if (t + 2 < nt) STAGE_TILE(As0, Bs0, (t + 2) * 32);
        COMPUTE_TILE(As1, Bs1);
        if (++t == nt) break;
        WAIT_BAR(t, nt);
        if (t + 2 < nt) STAGE_TILE(As1, Bs1, (t + 2) * 32);
        COMPUTE_TILE(As2, Bs2);
        if (++t == nt) break;
    }

    #pragma unroll
    for (int i = 0; i < 4; ++i) {
        #pragma unroll
        for (int j = 0; j < 4; ++j) {
            #pragma unroll
            for (int r = 0; r < 4; ++r) {
                int row = bm + wm + i * 16 + kh * 4 + r;
                int col = bn + wn + j * 16 + lr;
                float v = acc[i][j][r];
                if (bias) v += bias[col];
                if (act == 1) v = softplusf(v);
                if (Rres) v += Rres[(size_t)row * ldc + col];
                if (out16)
                    ((unsigned short*)C)[(size_t)row * ldc + col] = f2bf(v);
                else
                    C[(size_t)row * ldc + col] = v;
            }
        }
    }
}

// split-K skinny GEMM: Part[ks] = aconv16[bm:bm+128, ks*192:(ks+1)*192] @ Wcat16^T
__global__ __launch_bounds__(256) void gemm_skinny_bf16(
    const unsigned short* __restrict__ A, const unsigned short* __restrict__ B,
    float* __restrict__ Part)
{
    __shared__ unsigned short As0[128 * 32];
    __shared__ unsigned short Bs0[128 * 32];
    __shared__ unsigned short As1[128 * 32];
    __shared__ unsigned short Bs1[128 * 32];
    __shared__ unsigned short As2[128 * 32];
    __shared__ unsigned short Bs2[128 * 32];
    const int tid = threadIdx.x;
    const int wave = tid >> 6, lane = tid & 63;
    const int bm = blockIdx.x * 128;
    const int ks = blockIdx.y;
    const int k0 = ks * KSL;
    const int wm = (wave >> 1) * 64, wn = (wave & 1) * 64;
    const int lr = lane & 15, kh = lane >> 4;
    const int lda = DM, ldb = DM;

    f32x4 acc[4][4] = {};

    const unsigned short* Arow = A + (size_t)bm * DM;
    const unsigned short* Brow = B;   // 128 x DM

    const int nt = KSL >> 5;   // 6
    STAGE_TILE(As0, Bs0, k0);
    STAGE_TILE(As1, Bs1, k0 + 32);

    int t = 0;
    while (true) {
        WAIT_BAR(t, nt);
        if (t + 2 < nt) STAGE_TILE(As2, Bs2, k0 + (t + 2) * 32);
        COMPUTE_TILE(As0, Bs0);
        if (++t == nt) break;
        WAIT_BAR(t, nt);
        if (t + 2 < nt) STAGE_TILE(As0, Bs0, k0 + (t + 2) * 32);
        COMPUTE_TILE(As1, Bs1);
        if (++t == nt) break;
        WAIT_BAR(t, nt);
        if (t + 2 < nt) STAGE_TILE(As1, Bs1, k0 + (t + 2) * 32);
        COMPUTE_TILE(As2, Bs2);
        if (++t == nt) break;
    }

    float* out = Part + (size_t)ks * TT * NW;
    #pragma unroll
    for (int i = 0; i < 4; ++i) {
        #pragma unroll
        for (int j = 0; j < 4; ++j) {
            #pragma unroll
            for (int r = 0; r < 4; ++r) {
                int row = bm + wm + i * 16 + kh * 4 + r;
                int col = wn + j * 16 + lr;
                out[(size_t)row * NW + col] = acc[i][j][r];
            }
        }
    }
}

// sum KS partials; cols 0..31 -> BCD f32 (scans); cols 32..127 -> dd16 bf16 only.
__global__ void skinny_reduce(const float* __restrict__ Part,
                              float* __restrict__ BCD, unsigned short* __restrict__ dd16)
{
    int idx = blockIdx.x * 256 + threadIdx.x;     // over TT*NW
    float s = 0.f;
    #pragma unroll
    for (int ks = 0; ks < KS; ++ks)
        s += Part[(size_t)ks * TT * NW + idx];
    int col = idx & (NW - 1);
    if (col < 32) BCD[idx] = s;
    else          dd16[(size_t)(idx >> 7) * DD + (col - 32)] = f2bf(s);
}

// delta[t][d] = softplus(Dp[d] + dot96(dd1[t,:], W2[d,:])) -> dtv f32.
// Streaming: grid (DM/256, TT/16) = 1536 blocks (6/CU); dd1 tile in LDS,
// wave-uniform us8 broadcasts; W2 row in 96 f32 regs (no spill).
__global__ __launch_bounds__(256) void delta_kernel(
    const unsigned short* __restrict__ dd16, const unsigned short* __restrict__ W2,
    const float* __restrict__ Dp, float* __restrict__ dtv)
{
    __shared__ unsigned short sdd[16 * DD];   // [tt][k], 3 KB
    const int d = blockIdx.x * 256 + threadIdx.x;
    const int t0 = blockIdx.y * 16;

    for (int i = threadIdx.x; i < 16 * DD; i += 256)
        sdd[i] = dd16[(size_t)t0 * DD + i];

    float w[DD];
    {
        const uint4* wp = (const uint4*)(W2 + (size_t)d * DD);
        #pragma unroll
        for (int i = 0; i < DD / 8; ++i) {
            uint4 v = wp[i];
            const unsigned short* ps = (const unsigned short*)&v;
            #pragma unroll
            for (int e = 0; e < 8; ++e) w[i * 8 + e] = bf2f(ps[e]);
        }
    }
    float dpd = Dp[d];
    __syncthreads();

    for (int tt = 0; tt < 16; ++tt) {
        float acc = dpd;
        #pragma unroll
        for (int kk = 0; kk < DD / 8; ++kk) {
            us8 dv = *(const us8*)&sdd[tt * DD + kk * 8];   // wave-uniform broadcast
            #pragma unroll
            for (int e = 0; e < 8; ++e)
                acc += bf2f(dv[e]) * w[kk * 8 + e];
        }
        dtv[(size_t)(t0 + tt) * DM + d] = softplusf(acc);
    }
}

// causal depthwise conv (K=4) + silu -> aconv16 (bf16). Vectorized x8.
__global__ __launch_bounds__(192) void conv_silu_kernel(
    const unsigned short* __restrict__ proj16, const float* __restrict__ cw,
    const float* __restrict__ cb, unsigned short* __restrict__ aconv16)
{
    int t = blockIdx.x;
    int d0 = threadIdx.x * 8;
    int p = t & (SS - 1);

    float4 w[8];
    #pragma unroll
    for (int k = 0; k < 8; ++k) w[k] = ((const float4*)cw)[d0 + k];  // taps 0..3 for d0+k
    float acc[8];
    #pragma unroll
    for (int k = 0; k < 8; ++k) acc[k] = cb[d0 + k];

    #pragma unroll
    for (int j = 0; j < KC; ++j) {
        int pp = p - (KC - 1) + j;
        if (pp >= 0) {
            const unsigned short* rowp = proj16 + (size_t)(t - (KC - 1) + j) * (2 * DM) + d0;
            us4 lo = *(const us4*)rowp;
            us4 hi = *(const us4*)(rowp + 4);
            #pragma unroll
            for (int k = 0; k < 4; ++k) {
                acc[k]     += (&w[k].x)[j]     * bf2f(lo[k]);
                acc[4 + k] += (&w[4 + k].x)[j] * bf2f(hi[k]);
            }
        }
    }
    union { unsigned short s[8]; uint4 v; } o;
    #pragma unroll
    for (int k = 0; k < 8; ++k) o.s[k] = f2bf(siluf(acc[k]));
    *(uint4*)(aconv16 + (size_t)t * DM + d0) = o.v;
}

// pack [WB;WC;W1] -> Wcat16[l][128][DM] (bf16)
__global__ void concat_w_kernel(const float* __restrict__ WB, const float* __restrict__ WC,
                                const float* __restrict__ W1, unsigned short* __restrict__ Wcat16)
{
    int l = blockIdx.y;
    int row = blockIdx.x;
    const float* src;
    if (row < 16)      src = WB + (size_t)l * DS * DM + (size_t)row * DM;
    else if (row < 32) src = WC + (size_t)l * DS * DM + (size_t)(row - 16) * DM;
    else               src = W1 + (size_t)l * DD * DM + (size_t)(row - 32) * DM;
    unsigned short* dst = Wcat16 + ((size_t)l * NW + row) * DM;
    for (int i = threadIdx.x; i < DM / 4; i += 256) {
        float4 v = ((const float4*)src)[i];
        us4 u = { f2bf(v.x), f2bf(v.y), f2bf(v.z), f2bf(v.w) };
        *(us4*)(dst + i * 4) = u;
    }
}

// ---- chunk-parallel selective scan: thread-per-d, s-states in registers ----
// t-loop loads batched 8-wide: the per-step loads (dt, av) are independent of
// the recurrence, so issuing 8 up front amortizes load latency 8x (same fix
// that worked for scan_carry). Statically-indexed unrolled arrays (rule #20).
__global__ __launch_bounds__(256) void scan_pass1(
    const float* __restrict__ dtv, const unsigned short* __restrict__ av16,
    const float* __restrict__ BCD, const float* __restrict__ Amat,
    float2* __restrict__ PQ)
{
    __shared__ float4 sB4[CL][DS / 4];
    int b = blockIdx.z, c = blockIdx.y;
    int d = blockIdx.x * 256 + threadIdx.x;
    size_t rowbase = (size_t)b * SS + (size_t)c * CL;

    for (int i = threadIdx.x; i < CL * DS; i += 256)
        ((float*)sB4)[i] = BCD[(rowbase + (i >> 4)) * NW + (i & 15)];
    __syncthreads();

    float negA[DS], hid[DS];
    #pragma unroll
    for (int s = 0; s < DS; ++s) {
        negA[s] = -Amat[(size_t)d * DS + s];
        hid[s] = 0.f;
    }
    float cum = 0.f;

    const float* pd = dtv + rowbase * DM + d;
    const unsigned short* pa = av16 + rowbase * DM + d;
    for (int tb = 0; tb < CL; tb += 8) {
        float dts[8]; unsigned short avs[8];
        #pragma unroll
        for (int j = 0; j < 8; ++j) {
            dts[j] = pd[(size_t)(tb + j) * DM];
            avs[j] = pa[(size_t)(tb + j) * DM];
        }
        #pragma unroll
        for (int j = 0; j < 8; ++j) {
            int t = tb + j;
            float dt = dts[j];
            float avv = bf2f(avs[j]);
            cum += dt;
            float xv = dt * avv;
            #pragma unroll
            for (int q = 0; q < DS / 4; ++q) {
                float4 bv = sB4[t][q];
                hid[4*q+0] = __expf(dt * negA[4*q+0]) * hid[4*q+0] + xv * bv.x;
                hid[4*q+1] = __expf(dt * negA[4*q+1]) * hid[4*q+1] + xv * bv.y;
                hid[4*q+2] = __expf(dt * negA[4*q+2]) * hid[4*q+2] + xv * bv.z;
                hid[4*q+3] = __expf(dt * negA[4*q+3]) * hid[4*q+3] + xv * bv.w;
            }
        }
    }
    float2* out = PQ + ((size_t)(b * NCH + c) * DM + d) * DS;
    #pragma unroll
    for (int s = 0; s < DS; ++s)
        out[s] = make_float2(__expf(cum * negA[s]), hid[s]);
}

// 49152 chains, NCH sequential chunk steps each; rewrites .x = carry-in.
// Batched prefetch: 8 independent loads then 8 dependent FMAs.
__global__ void scan_carry(float2* __restrict__ PQ)
{
    int idx = blockIdx.x * 256 + threadIdx.x;
    int b = idx / (DM * DS);
    int r = idx - b * (DM * DS);
    float2* base = PQ + (size_t)b * NCH * (DM * DS) + r;
    float carry = 0.f;
    for (int cb = 0; cb < NCH; cb += 8) {
        float2 v[8];
        #pragma unroll
        for (int j = 0; j < 8; ++j)
            v[j] = base[(size_t)(cb + j) * (DM * DS)];
        #pragma unroll
        for (int j = 0; j < 8; ++j) {
            base[(size_t)(cb + j) * (DM * DS)].x = carry;
            carry = v[j].x * carry + v[j].y;
        }
    }
}

// pass2: re-run seeded with carry; y16 = bf16((hid·Cm + Dp*av) * silu(gate))
// t-loop loads (dt, av, gate) batched 8-wide, as in pass1.
__global__ __launch_bounds__(256) void scan_pass2(
    const float* __restrict__ dtv, const unsigned short* __restrict__ av16,
    const float* __restrict__ BCD,
    const unsigned short* __restrict__ proj16, const float* __restrict__ Amat,
    const float* __restrict__ Dp, const float2* __restrict__ PQ,
    unsigned short* __restrict__ y)
{
    __shared__ float4 sB4[CL][DS / 4];
    __shared__ float4 sC4[CL][DS / 4];
    int b = blockIdx.z, c = blockIdx.y;
    int d = blockIdx.x * 256 + threadIdx.x;
    size_t rowbase = (size_t)b * SS + (size_t)c * CL;

    for (int i = threadIdx.x; i < CL * DS; i += 256) {
        size_t row = rowbase + (i >> 4);
        ((float*)sB4)[i] = BCD[row * NW + (i & 15)];
        ((float*)sC4)[i] = BCD[row * NW + 16 + (i & 15)];
    }
    __syncthreads();

    float negA[DS], hid[DS];
    const float2* pin = PQ + ((size_t)(b * NCH + c) * DM + d) * DS;
    #pragma unroll
    for (int s = 0; s < DS; ++s) {
        negA[s] = -Amat[(size_t)d * DS + s];
        hid[s] = pin[s].x;            // carry-in
    }
    float Dpd = Dp[d];

    const float* pd = dtv + rowbase * DM + d;
    const unsigned short* pa = av16 + rowbase * DM + d;
    const unsigned short* gp = proj16 + rowbase * (2 * DM) + DM + d;
    unsigned short* yp = y + rowbase * DM + d;

    for (int tb = 0; tb < CL; tb += 8) {
        float dts[8]; unsigned short avs[8]; unsigned short gs[8];
        #pragma unroll
        for (int j = 0; j < 8; ++j) {
            dts[j] = pd[(size_t)(tb + j) * DM];
            avs[j] = pa[(size_t)(tb + j) * DM];
            gs[j]  = gp[(size_t)(tb + j) * (2 * DM)];
        }
        #pragma unroll
        for (int j = 0; j < 8; ++j) {
            int t = tb + j;
            float dt = dts[j];
            float avv = bf2f(avs[j]);
            float g  = bf2f(gs[j]);
            float xv = dt * avv;
            float acc0 = 0.f, acc1 = 0.f, acc2 = 0.f, acc3 = 0.f;
            #pragma unroll
            for (int q = 0; q < DS / 4; ++q) {
                float4 bv = sB4[t][q];
                float4 cv = sC4[t][q];
                hid[4*q+0] = __expf(dt * negA[4*q+0]) * hid[4*q+0] + xv * bv.x;
                hid[4*q+1] = __expf(dt * negA[4*q+1]) * hid[4*q+1] + xv * bv.y;
                hid[4*q+2] = __expf(dt * negA[4*q+2]) * hid[4*q+2] + xv * bv.z;
                hid[4*q+3] = __expf(dt * negA[4*q+3]) * hid[4*q+3] + xv * bv.w;
                acc0 += hid[4*q+0] * cv.x;
                acc1 += hid[4*q+1] * cv.y;
                acc2 += hid[4*q+2] * cv.z;
                acc3 += hid[4*q+3] * cv.w;
            }
            float contrib = (acc0 + acc1) + (acc2 + acc3);
            yp[(size_t)t * DM] = f2bf((contrib + Dpd * avv) * siluf(g));
        }
    }
}

// logits
__global__ void cls_kernel(const float* __restrict__ x, const float* __restrict__ W,
                           const float* __restrict__ bias, float* __restrict__ out)
{
    int t = blockIdx.x;
    int lane = threadIdx.x;
    const float* xr = x + (size_t)t * DI;
    float acc[NLAB];
    #pragma unroll
    for (int n = 0; n < NLAB; ++n) acc[n] = 0.f;
    for (int i = lane; i < DI; i += 64) {
        float xv = xr[i];
        #pragma unroll
        for (int n = 0; n < NLAB; ++n) acc[n] += xv * W[(size_t)n * DI + i];
    }
    #pragma unroll
    for (int n = 0; n < NLAB; ++n)
        #pragma unroll
        for (int m = 1; m < 64; m <<= 1) acc[n] += __shfl_xor(acc[n], m, 64);
    if (lane < NLAB) out[(size_t)t * NLAB + lane] = acc[lane] + bias[lane];
}

extern "C" void kernel_launch(void* const* d_in, const int* in_sizes, int n_in,
                              void* d_out, int out_size, void* d_ws, size_t ws_size,
                              hipStream_t stream)
{
    const int*   ids    = (const int*)d_in[0];
    const int*   mask   = (const int*)d_in[1];
    const float* emb    = (const float*)d_in[2];
    const float* norm_w = (const float*)d_in[3];
    const float* Wi     = (const float*)d_in[4];
    const float* conv_w = (const float*)d_in[5];
    const float* conv_b = (const float*)d_in[6];
    const float* sB_w   = (const float*)d_in[7];
    const float* sC_w   = (const float*)d_in[8];
    const float* sD1_w  = (const float*)d_in[9];
    const float* sD2_w  = (const float*)d_in[10];
    const float* Amat   = (const float*)d_in[11];
    const float* Dp     = (const float*)d_in[12];
    const float* out_w  = (const float*)d_in[13];
    const float* cls_w  = (const float*)d_in[14];
    const float* cls_b  = (const float*)d_in[15];
    float* logits = (float*)d_out;

    // workspace layout (float units)
    float* ws = (float*)d_ws;
    size_t off = 0;
    float* x     = ws + off; off += (size_t)TT * DI;
    unsigned short* proj16 = (unsigned short*)(ws + off); off += (size_t)TT * 2 * DM / 2;  // bf16 [a|gate]
    float* dtv   = ws + off; off += (size_t)TT * DM;   // softplus'd delta (planar f32)
    float* BCD   = ws + off; off += (size_t)TT * NW;
    // Part (KS*TT*NW = 4.2M fl) and PQ (BB*NCH*DM*DS*2 = 6.3M fl) are liveness-disjoint: share.
    size_t scratch_sz = (size_t)BB * NCH * DM * DS * 2;
    size_t part_sz = (size_t)KS * TT * NW;
    if (part_sz > scratch_sz) scratch_sz = part_sz;
    float* Part  = ws + off;
    float2* PQ   = (float2*)(ws + off); off += scratch_sz;
    unsigned short* y16     = (unsigned short*)(ws + off); off += (size_t)TT * DM / 2;
    unsigned short* aconv16 = (unsigned short*)(ws + off); off += (size_t)TT * DM / 2;
    unsigned short* Wi16    = (unsigned short*)(ws + off); off += (size_t)NL * 2 * DM * DI / 2;
    unsigned short* Wo16    = (unsigned short*)(ws + off); off += (size_t)NL * DI * DM / 2;
    unsigned short* W216    = (unsigned short*)(ws + off); off += (size_t)NL * DM * DD / 2;
    unsigned short* dd16    = (unsigned short*)(ws + off); off += (size_t)TT * DD / 2;
    unsigned short* Wcat16  = (unsigned short*)(ws + off); off += (size_t)NL * NW * DM / 2;
    if (ws_size < off * sizeof(float)) return;  // fail loud

    // h16 overlays dtv: h16 is dead after in_proj GEMM; dtv written only after that
    // (delta_kernel).
    unsigned short* h16 = (unsigned short*)dtv;

    embed_kernel<<<TT, DI / 4, 0, stream>>>(ids, mask, emb, x);
    concat_w_kernel<<<dim3(NW, NL), 256, 0, stream>>>(sB_w, sC_w, sD1_w, Wcat16);

    // whole-tensor weight conversions (all layers at once)
    f32_to_bf16<<<(NL * 2 * DM * DI / 8 + 255) / 256, 256, 0, stream>>>(Wi, Wi16, NL * 2 * DM * DI);
    f32_to_bf16<<<(NL * DI * DM / 8 + 255) / 256, 256, 0, stream>>>(out_w, Wo16, NL * DI * DM);
    f32_to_bf16<<<(NL * DM * DD / 8 + 255) / 256, 256, 0, stream>>>(sD2_w, W216, NL * DM * DD);

    for (int l = 0; l < NL; ++l) {
        const float* cw_l  = conv_w + (size_t)l * DM * KC;
        const float* cb_l  = conv_b + (size_t)l * DM;
        const float* A_l   = Amat  + (size_t)l * DM * DS;
        const float* Dp_l  = Dp    + (size_t)l * DM;
        const float* nw_l  = norm_w + (size_t)l * DI;
        const unsigned short* Wi16_l  = Wi16  + (size_t)l * 2 * DM * DI;
        const unsigned short* Wo16_l  = Wo16  + (size_t)l * DI * DM;
        const unsigned short* W216_l  = W216  + (size_t)l * DM * DD;
        const unsigned short* Wcat16_l = Wcat16 + (size_t)l * NW * DM;

        rmsnorm_kernel<<<TT, DI / 4, 0, stream>>>(x, nw_l, h16);

        // proj16 = bf16(h @ Wi^T) : M=TT, N=2*DM, K=DI  (128^2 3-buf pipeline)
        gemm_bf16<<<dim3(2 * DM / 128, TT / 128), 256, 0, stream>>>(
            h16, Wi16_l, nullptr, nullptr, (float*)proj16, TT, 2 * DM, DI, DI, DI, 2 * DM, 0, 1);

        conv_silu_kernel<<<TT, DM / 8, 0, stream>>>(proj16, cw_l, cb_l, aconv16);

        // BCD = aconv @ Wcat^T (Bm | Cm | dd1), split-K MFMA + reduce
        gemm_skinny_bf16<<<dim3(TT / 128, KS), 256, 0, stream>>>(aconv16, Wcat16_l, Part);
        skinny_reduce<<<TT * NW / 256, 256, 0, stream>>>(Part, BCD, dd16);

        // delta = softplus(Dp + dd1 @ W2^T) -> dtv (streaming, 1536 blocks)
        delta_kernel<<<dim3(DM / 256, TT / 16), 256, 0, stream>>>(dd16, W216_l, Dp_l, dtv);

        // chunk-parallel scan (thread-per-d)
        scan_pass1<<<dim3(DM / 256, NCH, BB), 256, 0, stream>>>(dtv, aconv16, BCD, A_l, PQ);
        scan_carry<<<BB * DM * DS / 256, 256, 0, stream>>>(PQ);
        scan_pass2<<<dim3(DM / 256, NCH, BB), 256, 0, stream>>>(
            dtv, aconv16, BCD, proj16, A_l, Dp_l, PQ, y16);

        // x = x + y @ Wo^T : M=TT, N=DI, K=DM  (128^2 3-buf pipeline)
        gemm_bf16<<<dim3(DI / 128, TT / 128), 256, 0, stream>>>(
            y16, Wo16_l, x, nullptr, x, TT, DI, DM, DM, DM, DI, 0, 0);
    }

    cls_kernel<<<TT, 64, 0, stream>>>(x, cls_w, cls_b, logits);
}

// Round 11
// 677.473 us; speedup vs baseline: 1.0739x; 1.0739x over previous
//
#include <hip/hip_runtime.h>
#include <hip/hip_bf16.h>
#include <math.h>

// Problem constants
#define NLAB 9
#define NL   2
#define DI   768
#define DM   1536
#define DS   16
#define KC   4
#define DD   96
#define BB   2
#define SS   2048
#define TT   (BB*SS)
#define EPSF 1e-6f

// chunked scan config
#define NCH  64
#define CL   (SS/NCH)   // 32

// skinny fused projection width: 16 (B) + 16 (C) + 96 (dd1)
#define NW   128
// split-K factor for the skinny GEMM (K=DM=1536 -> 8 x 192)
#define KS   8
#define KSL  (DM/KS)    // 192

typedef __attribute__((ext_vector_type(4))) float f32x4;
typedef __attribute__((ext_vector_type(8))) short bf16x8;
typedef __attribute__((ext_vector_type(4))) unsigned short us4;
typedef __attribute__((ext_vector_type(8))) unsigned short us8;

__device__ __forceinline__ float siluf(float x) { return x / (1.f + __expf(-x)); }
__device__ __forceinline__ float softplusf(float x) { return x > 15.f ? x : log1pf(__expf(x)); }

// f32 -> bf16 (RNE, finite inputs)
__device__ __forceinline__ unsigned short f2bf(float f) {
    unsigned u = __float_as_uint(f);
    return (unsigned short)((u + 0x7fffu + ((u >> 16) & 1u)) >> 16);
}
__device__ __forceinline__ float bf2f(unsigned short s) {
    return __uint_as_float((unsigned)s << 16);
}

// XCD-aware tile map: HW round-robins flat block id across 8 XCDs (flat&7).
// Square per-XCD regions so the working set fits the 4 MiB per-XCD L2.
__device__ __forceinline__ void xcd_map(int gx, int gy, int bx, int by,
                                        int& bmt, int& bnt)
{
    int flat = by * gx + bx;
    if ((gx & 1) == 0 && (gy & 3) == 0) {
        int halfx = gx >> 1, quarty = gy >> 2;
        int xcd = flat & 7, local = flat >> 3;
        bnt = (xcd & 1) * halfx + local % halfx;
        bmt = (xcd >> 1) * quarty + local / halfx;
    } else { bmt = by; bnt = bx; }
}

__global__ void f32_to_bf16(const float* __restrict__ src,
                            unsigned short* __restrict__ dst, int n)
{
    int i = (blockIdx.x * 256 + threadIdx.x) * 8;
    if (i >= n) return;
    float4 a = *(const float4*)(src + i);
    float4 b = *(const float4*)(src + i + 4);
    union { unsigned short s[8]; uint4 v; } o;
    o.s[0] = f2bf(a.x); o.s[1] = f2bf(a.y); o.s[2] = f2bf(a.z); o.s[3] = f2bf(a.w);
    o.s[4] = f2bf(b.x); o.s[5] = f2bf(b.y); o.s[6] = f2bf(b.z); o.s[7] = f2bf(b.w);
    *(uint4*)(dst + i) = o.v;
}

// x[t,:] = emb[ids[t],:] * mask[t]
__global__ void embed_kernel(const int* __restrict__ ids, const int* __restrict__ mask,
                             const float* __restrict__ emb, float* __restrict__ x)
{
    int t = blockIdx.x;
    int i = threadIdx.x;
    float m = (float)mask[t];
    int id = ids[t];
    float4 v = ((const float4*)(emb + (size_t)id * DI))[i];
    v.x *= m; v.y *= m; v.z *= m; v.w *= m;
    ((float4*)(x + (size_t)t * DI))[i] = v;
}

// h16[t,:] = bf16( x[t,:] * rsqrt(mean(x^2)+eps) * w )  — float4-vectorized (G13)
__global__ __launch_bounds__(192) void rmsnorm_kernel(
    const float* __restrict__ x, const float* __restrict__ w,
    unsigned short* __restrict__ h)
{
    __shared__ float red[3];
    int t = blockIdx.x;
    float4 v = ((const float4*)(x + (size_t)t * DI))[threadIdx.x];
    float ss = v.x * v.x + v.y * v.y + v.z * v.z + v.w * v.w;
    #pragma unroll
    for (int m = 1; m < 64; m <<= 1) ss += __shfl_xor(ss, m, 64);
    if ((threadIdx.x & 63) == 0) red[threadIdx.x >> 6] = ss;
    __syncthreads();
    float scale = rsqrtf((red[0] + red[1] + red[2]) * (1.f / DI) + EPSF);
    float4 wv = ((const float4*)w)[threadIdx.x];
    us4 o = { f2bf(v.x * scale * wv.x), f2bf(v.y * scale * wv.y),
              f2bf(v.z * scale * wv.z), f2bf(v.w * scale * wv.w) };
    *(us4*)(h + (size_t)t * DI + threadIdx.x * 4) = o;
}

// ---- 64x128 bf16 MFMA GEMM: 3-buffer pipeline, counted vmcnt ----
// Geometry refcheck-proven (round-8 skinny): 4 waves (2Mx2N), acc[2][4],
// LDS 36KB -> 4 blocks/CU resident (vs 3 at 128^2) and 2x the grid size:
// block-level concurrency is what hides the per-tile barrier drain (m114).
// Same chunk-XOR LDS swizzle (both-sides involution; row bases are multiples
// of 16 so both identities hold; SQ_LDS_BANK_CONFLICT measured 0).
#define STAGE_T64(AS, BS, KT) do {                                                            \
    {                                                                                         \
        int rbase = wave * 16;                                                                \
        int row = rbase + (lane >> 2);                                                        \
        int c8 = (((lane & 3) ^ ((lane >> 3) & 3)) * 8);                                      \
        __builtin_amdgcn_global_load_lds(                                                     \
            (const __attribute__((address_space(1))) unsigned int*)(Arow + (size_t)row * lda + (KT) + c8), \
            (__attribute__((address_space(3))) unsigned int*)((AS) + rbase * 32), 16, 0, 0);  \
    }                                                                                         \
    _Pragma("unroll")                                                                         \
    for (int it = 0; it < 2; ++it) {                                                          \
        int rbase = it * 64 + wave * 16;                                                      \
        int row = rbase + (lane >> 2);                                                        \
        int c8 = (((lane & 3) ^ ((lane >> 3) & 3)) * 8);                                      \
        __builtin_amdgcn_global_load_lds(                                                     \
            (const __attribute__((address_space(1))) unsigned int*)(Brow + (size_t)row * ldb + (KT) + c8), \
            (__attribute__((address_space(3))) unsigned int*)((BS) + rbase * 32), 16, 0, 0);  \
    } } while (0)

#define COMPUTE_T64(AS, BS) do {                                                              \
    bf16x8 af[2], bfr[4];                                                                     \
    const int khs = (kh ^ ((lr >> 1) & 3)) * 8;                                               \
    _Pragma("unroll")                                                                         \
    for (int i = 0; i < 2; ++i)                                                               \
        af[i] = *(const bf16x8*)&(AS)[(wm + i * 16 + lr) * 32 + khs];                         \
    _Pragma("unroll")                                                                         \
    for (int j = 0; j < 4; ++j)                                                               \
        bfr[j] = *(const bf16x8*)&(BS)[(wn + j * 16 + lr) * 32 + khs];                        \
    _Pragma("unroll")                                                                         \
    for (int i = 0; i < 2; ++i)                                                               \
        _Pragma("unroll")                                                                     \
        for (int j = 0; j < 4; ++j)                                                           \
            acc[i][j] = __builtin_amdgcn_mfma_f32_16x16x32_bf16(af[i], bfr[j], acc[i][j], 0, 0, 0); \
    } while (0)

#define WAIT_BAR3(T, NT) do {                                                                 \
    if ((T) + 1 < (NT)) asm volatile("s_waitcnt vmcnt(3)" ::: "memory");                      \
    else                asm volatile("s_waitcnt vmcnt(0)" ::: "memory");                      \
    __builtin_amdgcn_s_barrier();                                                             \
} while (0)

// out16: when 1, C is written as bf16 (ushort*), act/bias/Rres still applied in f32.
__global__ __launch_bounds__(256) void gemm_bf16(
    const unsigned short* __restrict__ A, const unsigned short* __restrict__ B,
    const float* __restrict__ Rres, const float* __restrict__ bias,
    float* __restrict__ C, int M, int N, int K,
    int lda, int ldb, int ldc, int act, int out16)
{
    __shared__ unsigned short As0[64 * 32];
    __shared__ unsigned short Bs0[128 * 32];
    __shared__ unsigned short As1[64 * 32];
    __shared__ unsigned short Bs1[128 * 32];
    __shared__ unsigned short As2[64 * 32];
    __shared__ unsigned short Bs2[128 * 32];
    const int tid = threadIdx.x;
    const int wave = tid >> 6, lane = tid & 63;

    int bmt, bnt;
    xcd_map(gridDim.x, gridDim.y, blockIdx.x, blockIdx.y, bmt, bnt);
    const int bm = bmt * 64, bn = bnt * 128;

    const int wm = (wave >> 1) * 32, wn = (wave & 1) * 64;
    const int lr = lane & 15, kh = lane >> 4;

    f32x4 acc[2][4] = {};

    const unsigned short* Arow = A + (size_t)bm * lda;
    const unsigned short* Brow = B + (size_t)bn * ldb;

    const int nt = K >> 5;
    STAGE_T64(As0, Bs0, 0);
    STAGE_T64(As1, Bs1, 32);

    int t = 0;
    while (true) {
        WAIT_BAR3(t, nt);
        if (t + 2 < nt) STAGE_T64(As2, Bs2, (t + 2) * 32);
        COMPUTE_T64(As0, Bs0);
        if (++t == nt) break;
        WAIT_BAR3(t, nt);
        if (t + 2 < nt) STAGE_T64(As0, Bs0, (t + 2) * 32);
        COMPUTE_T64(As1, Bs1);
        if (++t == nt) break;
        WAIT_BAR3(t, nt);
        if (t + 2 < nt) STAGE_T64(As1, Bs1, (t + 2) * 32);
        COMPUTE_T64(As2, Bs2);
        if (++t == nt) break;
    }

    #pragma unroll
    for (int i = 0; i < 2; ++i) {
        #pragma unroll
        for (int j = 0; j < 4; ++j) {
            #pragma unroll
            for (int r = 0; r < 4; ++r) {
                int row = bm + wm + i * 16 + kh * 4 + r;
                int col = bn + wn + j * 16 + lr;
                float v = acc[i][j][r];
                if (bias) v += bias[col];
                if (act == 1) v = softplusf(v);
                if (Rres) v += Rres[(size_t)row * ldc + col];
                if (out16)
                    ((unsigned short*)C)[(size_t)row * ldc + col] = f2bf(v);
                else
                    C[(size_t)row * ldc + col] = v;
            }
        }
    }
}

// split-K skinny GEMM: Part[ks] = aconv16[bm:bm+128, ks*192:(ks+1)*192] @ Wcat16^T
// (128-row tiles, validated round-7 state)
#define STAGE_TILE(AS, BS, KT) do {                                                           \
    _Pragma("unroll")                                                                         \
    for (int it = 0; it < 2; ++it) {                                                          \
        int rbase = it * 64 + wave * 16;                                                      \
        int row = rbase + (lane >> 2);                                                        \
        int c8 = (((lane & 3) ^ ((lane >> 3) & 3)) * 8);                                      \
        __builtin_amdgcn_global_load_lds(                                                     \
            (const __attribute__((address_space(1))) unsigned int*)(Arow + (size_t)row * lda + (KT) + c8), \
            (__attribute__((address_space(3))) unsigned int*)((AS) + rbase * 32), 16, 0, 0);  \
        __builtin_amdgcn_global_load_lds(                                                     \
            (const __attribute__((address_space(1))) unsigned int*)(Brow + (size_t)row * ldb + (KT) + c8), \
            (__attribute__((address_space(3))) unsigned int*)((BS) + rbase * 32), 16, 0, 0);  \
    } } while (0)

#define COMPUTE_TILE(AS, BS) do {                                                             \
    bf16x8 af[4], bfr[4];                                                                     \
    const int khs = (kh ^ ((lr >> 1) & 3)) * 8;                                               \
    _Pragma("unroll")                                                                         \
    for (int i = 0; i < 4; ++i)                                                               \
        af[i] = *(const bf16x8*)&(AS)[(wm + i * 16 + lr) * 32 + khs];                         \
    _Pragma("unroll")                                                                         \
    for (int j = 0; j < 4; ++j)                                                               \
        bfr[j] = *(const bf16x8*)&(BS)[(wn + j * 16 + lr) * 32 + khs];                        \
    _Pragma("unroll")                                                                         \
    for (int i = 0; i < 4; ++i)                                                               \
        _Pragma("unroll")                                                                     \
        for (int j = 0; j < 4; ++j)                                                           \
            acc[i][j] = __builtin_amdgcn_mfma_f32_16x16x32_bf16(af[i], bfr[j], acc[i][j], 0, 0, 0); \
    } while (0)

#define WAIT_BAR(T, NT) do {                                                                  \
    if ((T) + 1 < (NT)) asm volatile("s_waitcnt vmcnt(4)" ::: "memory");                      \
    else                asm volatile("s_waitcnt vmcnt(0)" ::: "memory");                      \
    __builtin_amdgcn_s_barrier();                                                             \
} while (0)

__global__ __launch_bounds__(256) void gemm_skinny_bf16(
    const unsigned short* __restrict__ A, const unsigned short* __restrict__ B,
    float* __restrict__ Part)
{
    __shared__ unsigned short As0[128 * 32];
    __shared__ unsigned short Bs0[128 * 32];
    __shared__ unsigned short As1[128 * 32];
    __shared__ unsigned short Bs1[128 * 32];
    __shared__ unsigned short As2[128 * 32];
    __shared__ unsigned short Bs2[128 * 32];
    const int tid = threadIdx.x;
    const int wave = tid >> 6, lane = tid & 63;
    const int bm = blockIdx.x * 128;
    const int ks = blockIdx.y;
    const int k0 = ks * KSL;
    const int wm = (wave >> 1) * 64, wn = (wave & 1) * 64;
    const int lr = lane & 15, kh = lane >> 4;
    const int lda = DM, ldb = DM;

    f32x4 acc[4][4] = {};

    const unsigned short* Arow = A + (size_t)bm * DM;
    const unsigned short* Brow = B;   // 128 x DM

    const int nt = KSL >> 5;   // 6
    STAGE_TILE(As0, Bs0, k0);
    STAGE_TILE(As1, Bs1, k0 + 32);

    int t = 0;
    while (true) {
        WAIT_BAR(t, nt);
        if (t + 2 < nt) STAGE_TILE(As2, Bs2, k0 + (t + 2) * 32);
        COMPUTE_TILE(As0, Bs0);
        if (++t == nt) break;
        WAIT_BAR(t, nt);
        if (t + 2 < nt) STAGE_TILE(As0, Bs0, k0 + (t + 2) * 32);
        COMPUTE_TILE(As1, Bs1);
        if (++t == nt) break;
        WAIT_BAR(t, nt);
        if (t + 2 < nt) STAGE_TILE(As1, Bs1, k0 + (t + 2) * 32);
        COMPUTE_TILE(As2, Bs2);
        if (++t == nt) break;
    }

    float* out = Part + (size_t)ks * TT * NW;
    #pragma unroll
    for (int i = 0; i < 4; ++i) {
        #pragma unroll
        for (int j = 0; j < 4; ++j) {
            #pragma unroll
            for (int r = 0; r < 4; ++r) {
                int row = bm + wm + i * 16 + kh * 4 + r;
                int col = wn + j * 16 + lr;
                out[(size_t)row * NW + col] = acc[i][j][r];
            }
        }
    }
}

// sum KS partials; cols 0..31 -> BCD f32 (scans); cols 32..127 -> dd16 bf16 only.
__global__ void skinny_reduce(const float* __restrict__ Part,
                              float* __restrict__ BCD, unsigned short* __restrict__ dd16)
{
    int idx = blockIdx.x * 256 + threadIdx.x;     // over TT*NW
    float s = 0.f;
    #pragma unroll
    for (int ks = 0; ks < KS; ++ks)
        s += Part[(size_t)ks * TT * NW + idx];
    int col = idx & (NW - 1);
    if (col < 32) BCD[idx] = s;
    else          dd16[(size_t)(idx >> 7) * DD + (col - 32)] = f2bf(s);
}

// delta[t][d] = softplus(Dp[d] + dot96(dd1[t,:], W2[d,:])) -> dtv f32.
// Streaming: grid (DM/256, TT/16) = 1536 blocks (6/CU); dd1 tile in LDS,
// wave-uniform us8 broadcasts; W2 row in 96 f32 regs (no spill).
__global__ __launch_bounds__(256) void delta_kernel(
    const unsigned short* __restrict__ dd16, const unsigned short* __restrict__ W2,
    const float* __restrict__ Dp, float* __restrict__ dtv)
{
    __shared__ unsigned short sdd[16 * DD];   // [tt][k], 3 KB
    const int d = blockIdx.x * 256 + threadIdx.x;
    const int t0 = blockIdx.y * 16;

    for (int i = threadIdx.x; i < 16 * DD; i += 256)
        sdd[i] = dd16[(size_t)t0 * DD + i];

    float w[DD];
    {
        const uint4* wp = (const uint4*)(W2 + (size_t)d * DD);
        #pragma unroll
        for (int i = 0; i < DD / 8; ++i) {
            uint4 v = wp[i];
            const unsigned short* ps = (const unsigned short*)&v;
            #pragma unroll
            for (int e = 0; e < 8; ++e) w[i * 8 + e] = bf2f(ps[e]);
        }
    }
    float dpd = Dp[d];
    __syncthreads();

    for (int tt = 0; tt < 16; ++tt) {
        float acc = dpd;
        #pragma unroll
        for (int kk = 0; kk < DD / 8; ++kk) {
            us8 dv = *(const us8*)&sdd[tt * DD + kk * 8];   // wave-uniform broadcast
            #pragma unroll
            for (int e = 0; e < 8; ++e)
                acc += bf2f(dv[e]) * w[kk * 8 + e];
        }
        dtv[(size_t)(t0 + tt) * DM + d] = softplusf(acc);
    }
}

// causal depthwise conv (K=4) + silu -> aconv16 (bf16). Vectorized x8.
__global__ __launch_bounds__(192) void conv_silu_kernel(
    const unsigned short* __restrict__ proj16, const float* __restrict__ cw,
    const float* __restrict__ cb, unsigned short* __restrict__ aconv16)
{
    int t = blockIdx.x;
    int d0 = threadIdx.x * 8;
    int p = t & (SS - 1);

    float4 w[8];
    #pragma unroll
    for (int k = 0; k < 8; ++k) w[k] = ((const float4*)cw)[d0 + k];  // taps 0..3 for d0+k
    float acc[8];
    #pragma unroll
    for (int k = 0; k < 8; ++k) acc[k] = cb[d0 + k];

    #pragma unroll
    for (int j = 0; j < KC; ++j) {
        int pp = p - (KC - 1) + j;
        if (pp >= 0) {
            const unsigned short* rowp = proj16 + (size_t)(t - (KC - 1) + j) * (2 * DM) + d0;
            us4 lo = *(const us4*)rowp;
            us4 hi = *(const us4*)(rowp + 4);
            #pragma unroll
            for (int k = 0; k < 4; ++k) {
                acc[k]     += (&w[k].x)[j]     * bf2f(lo[k]);
                acc[4 + k] += (&w[4 + k].x)[j] * bf2f(hi[k]);
            }
        }
    }
    union { unsigned short s[8]; uint4 v; } o;
    #pragma unroll
    for (int k = 0; k < 8; ++k) o.s[k] = f2bf(siluf(acc[k]));
    *(uint4*)(aconv16 + (size_t)t * DM + d0) = o.v;
}

// pack [WB;WC;W1] -> Wcat16[l][128][DM] (bf16)
__global__ void concat_w_kernel(const float* __restrict__ WB, const float* __restrict__ WC,
                                const float* __restrict__ W1, unsigned short* __restrict__ Wcat16)
{
    int l = blockIdx.y;
    int row = blockIdx.x;
    const float* src;
    if (row < 16)      src = WB + (size_t)l * DS * DM + (size_t)row * DM;
    else if (row < 32) src = WC + (size_t)l * DS * DM + (size_t)(row - 16) * DM;
    else               src = W1 + (size_t)l * DD * DM + (size_t)(row - 32) * DM;
    unsigned short* dst = Wcat16 + ((size_t)l * NW + row) * DM;
    for (int i = threadIdx.x; i < DM / 4; i += 256) {
        float4 v = ((const float4*)src)[i];
        us4 u = { f2bf(v.x), f2bf(v.y), f2bf(v.z), f2bf(v.w) };
        *(us4*)(dst + i * 4) = u;
    }
}

// ---- chunk-parallel selective scan: thread-per-d, s-states in registers ----
__global__ __launch_bounds__(256) void scan_pass1(
    const float* __restrict__ dtv, const unsigned short* __restrict__ av16,
    const float* __restrict__ BCD, const float* __restrict__ Amat,
    float2* __restrict__ PQ)
{
    __shared__ float4 sB4[CL][DS / 4];
    int b = blockIdx.z, c = blockIdx.y;
    int d = blockIdx.x * 256 + threadIdx.x;
    size_t rowbase = (size_t)b * SS + (size_t)c * CL;

    for (int i = threadIdx.x; i < CL * DS; i += 256)
        ((float*)sB4)[i] = BCD[(rowbase + (i >> 4)) * NW + (i & 15)];
    __syncthreads();

    float negA[DS], hid[DS];
    #pragma unroll
    for (int s = 0; s < DS; ++s) {
        negA[s] = -Amat[(size_t)d * DS + s];
        hid[s] = 0.f;
    }
    float cum = 0.f;

    const float* pd = dtv + rowbase * DM + d;
    const unsigned short* pa = av16 + rowbase * DM + d;
    for (int t = 0; t < CL; ++t) {
        float dt = pd[(size_t)t * DM];
        float avv = bf2f(pa[(size_t)t * DM]);
        cum += dt;
        float xv = dt * avv;
        #pragma unroll
        for (int j = 0; j < DS / 4; ++j) {
            float4 bv = sB4[t][j];
            hid[4*j+0] = __expf(dt * negA[4*j+0]) * hid[4*j+0] + xv * bv.x;
            hid[4*j+1] = __expf(dt * negA[4*j+1]) * hid[4*j+1] + xv * bv.y;
            hid[4*j+2] = __expf(dt * negA[4*j+2]) * hid[4*j+2] + xv * bv.z;
            hid[4*j+3] = __expf(dt * negA[4*j+3]) * hid[4*j+3] + xv * bv.w;
        }
    }
    float2* out = PQ + ((size_t)(b * NCH + c) * DM + d) * DS;
    #pragma unroll
    for (int s = 0; s < DS; ++s)
        out[s] = make_float2(__expf(cum * negA[s]), hid[s]);
}

// 49152 chains, NCH sequential chunk steps each; rewrites .x = carry-in.
// Batched prefetch: 8 independent loads then 8 dependent FMAs.
__global__ void scan_carry(float2* __restrict__ PQ)
{
    int idx = blockIdx.x * 256 + threadIdx.x;
    int b = idx / (DM * DS);
    int r = idx - b * (DM * DS);
    float2* base = PQ + (size_t)b * NCH * (DM * DS) + r;
    float carry = 0.f;
    for (int cb = 0; cb < NCH; cb += 8) {
        float2 v[8];
        #pragma unroll
        for (int j = 0; j < 8; ++j)
            v[j] = base[(size_t)(cb + j) * (DM * DS)];
        #pragma unroll
        for (int j = 0; j < 8; ++j) {
            base[(size_t)(cb + j) * (DM * DS)].x = carry;
            carry = v[j].x * carry + v[j].y;
        }
    }
}

// pass2: re-run seeded with carry; y16 = bf16((hid·Cm + Dp*av) * silu(gate))
__global__ __launch_bounds__(256) void scan_pass2(
    const float* __restrict__ dtv, const unsigned short* __restrict__ av16,
    const float* __restrict__ BCD,
    const unsigned short* __restrict__ proj16, const float* __restrict__ Amat,
    const float* __restrict__ Dp, const float2* __restrict__ PQ,
    unsigned short* __restrict__ y)
{
    __shared__ float4 sB4[CL][DS / 4];
    __shared__ float4 sC4[CL][DS / 4];
    int b = blockIdx.z, c = blockIdx.y;
    int d = blockIdx.x * 256 + threadIdx.x;
    size_t rowbase = (size_t)b * SS + (size_t)c * CL;

    for (int i = threadIdx.x; i < CL * DS; i += 256) {
        size_t row = rowbase + (i >> 4);
        ((float*)sB4)[i] = BCD[row * NW + (i & 15)];
        ((float*)sC4)[i] = BCD[row * NW + 16 + (i & 15)];
    }
    __syncthreads();

    float negA[DS], hid[DS];
    const float2* pin = PQ + ((size_t)(b * NCH + c) * DM + d) * DS;
    #pragma unroll
    for (int s = 0; s < DS; ++s) {
        negA[s] = -Amat[(size_t)d * DS + s];
        hid[s] = pin[s].x;            // carry-in
    }
    float Dpd = Dp[d];

    const float* pd = dtv + rowbase * DM + d;
    const unsigned short* pa = av16 + rowbase * DM + d;
    const unsigned short* gp = proj16 + rowbase * (2 * DM) + DM + d;
    unsigned short* yp = y + rowbase * DM + d;

    for (int t = 0; t < CL; ++t) {
        float dt = pd[(size_t)t * DM];
        float avv = bf2f(pa[(size_t)t * DM]);
        float g  = bf2f(gp[(size_t)t * (2 * DM)]);
        float xv = dt * avv;
        float acc0 = 0.f, acc1 = 0.f, acc2 = 0.f, acc3 = 0.f;
        #pragma unroll
        for (int j = 0; j < DS / 4; ++j) {
            float4 bv = sB4[t][j];
            float4 cv = sC4[t][j];
            hid[4*j+0] = __expf(dt * negA[4*j+0]) * hid[4*j+0] + xv * bv.x;
            hid[4*j+1] = __expf(dt * negA[4*j+1]) * hid[4*j+1] + xv * bv.y;
            hid[4*j+2] = __expf(dt * negA[4*j+2]) * hid[4*j+2] + xv * bv.z;
            hid[4*j+3] = __expf(dt * negA[4*j+3]) * hid[4*j+3] + xv * bv.w;
            acc0 += hid[4*j+0] * cv.x;
            acc1 += hid[4*j+1] * cv.y;
            acc2 += hid[4*j+2] * cv.z;
            acc3 += hid[4*j+3] * cv.w;
        }
        float contrib = (acc0 + acc1) + (acc2 + acc3);
        yp[(size_t)t * DM] = f2bf((contrib + Dpd * avv) * siluf(g));
    }
}

// logits
__global__ void cls_kernel(const float* __restrict__ x, const float* __restrict__ W,
                           const float* __restrict__ bias, float* __restrict__ out)
{
    int t = blockIdx.x;
    int lane = threadIdx.x;
    const float* xr = x + (size_t)t * DI;
    float acc[NLAB];
    #pragma unroll
    for (int n = 0; n < NLAB; ++n) acc[n] = 0.f;
    for (int i = lane; i < DI; i += 64) {
        float xv = xr[i];
        #pragma unroll
        for (int n = 0; n < NLAB; ++n) acc[n] += xv * W[(size_t)n * DI + i];
    }
    #pragma unroll
    for (int n = 0; n < NLAB; ++n)
        #pragma unroll
        for (int m = 1; m < 64; m <<= 1) acc[n] += __shfl_xor(acc[n], m, 64);
    if (lane < NLAB) out[(size_t)t * NLAB + lane] = acc[lane] + bias[lane];
}

extern "C" void kernel_launch(void* const* d_in, const int* in_sizes, int n_in,
                              void* d_out, int out_size, void* d_ws, size_t ws_size,
                              hipStream_t stream)
{
    const int*   ids    = (const int*)d_in[0];
    const int*   mask   = (const int*)d_in[1];
    const float* emb    = (const float*)d_in[2];
    const float* norm_w = (const float*)d_in[3];
    const float* Wi     = (const float*)d_in[4];
    const float* conv_w = (const float*)d_in[5];
    const float* conv_b = (const float*)d_in[6];
    const float* sB_w   = (const float*)d_in[7];
    const float* sC_w   = (const float*)d_in[8];
    const float* sD1_w  = (const float*)d_in[9];
    const float* sD2_w  = (const float*)d_in[10];
    const float* Amat   = (const float*)d_in[11];
    const float* Dp     = (const float*)d_in[12];
    const float* out_w  = (const float*)d_in[13];
    const float* cls_w  = (const float*)d_in[14];
    const float* cls_b  = (const float*)d_in[15];
    float* logits = (float*)d_out;

    // workspace layout (float units)
    float* ws = (float*)d_ws;
    size_t off = 0;
    float* x     = ws + off; off += (size_t)TT * DI;
    unsigned short* proj16 = (unsigned short*)(ws + off); off += (size_t)TT * 2 * DM / 2;  // bf16 [a|gate]
    float* dtv   = ws + off; off += (size_t)TT * DM;   // softplus'd delta (planar f32)
    float* BCD   = ws + off; off += (size_t)TT * NW;
    // Part (KS*TT*NW = 4.2M fl) and PQ (BB*NCH*DM*DS*2 = 6.3M fl) are liveness-disjoint: share.
    size_t scratch_sz = (size_t)BB * NCH * DM * DS * 2;
    size_t part_sz = (size_t)KS * TT * NW;
    if (part_sz > scratch_sz) scratch_sz = part_sz;
    float* Part  = ws + off;
    float2* PQ   = (float2*)(ws + off); off += scratch_sz;
    unsigned short* y16     = (unsigned short*)(ws + off); off += (size_t)TT * DM / 2;
    unsigned short* aconv16 = (unsigned short*)(ws + off); off += (size_t)TT * DM / 2;
    unsigned short* Wi16    = (unsigned short*)(ws + off); off += (size_t)NL * 2 * DM * DI / 2;
    unsigned short* Wo16    = (unsigned short*)(ws + off); off += (size_t)NL * DI * DM / 2;
    unsigned short* W216    = (unsigned short*)(ws + off); off += (size_t)NL * DM * DD / 2;
    unsigned short* dd16    = (unsigned short*)(ws + off); off += (size_t)TT * DD / 2;
    unsigned short* Wcat16  = (unsigned short*)(ws + off); off += (size_t)NL * NW * DM / 2;
    if (ws_size < off * sizeof(float)) return;  // fail loud

    // h16 overlays dtv: h16 is dead after in_proj GEMM; dtv written only after that
    // (delta_kernel).
    unsigned short* h16 = (unsigned short*)dtv;

    embed_kernel<<<TT, DI / 4, 0, stream>>>(ids, mask, emb, x);
    concat_w_kernel<<<dim3(NW, NL), 256, 0, stream>>>(sB_w, sC_w, sD1_w, Wcat16);

    // whole-tensor weight conversions (all layers at once)
    f32_to_bf16<<<(NL * 2 * DM * DI / 8 + 255) / 256, 256, 0, stream>>>(Wi, Wi16, NL * 2 * DM * DI);
    f32_to_bf16<<<(NL * DI * DM / 8 + 255) / 256, 256, 0, stream>>>(out_w, Wo16, NL * DI * DM);
    f32_to_bf16<<<(NL * DM * DD / 8 + 255) / 256, 256, 0, stream>>>(sD2_w, W216, NL * DM * DD);

    for (int l = 0; l < NL; ++l) {
        const float* cw_l  = conv_w + (size_t)l * DM * KC;
        const float* cb_l  = conv_b + (size_t)l * DM;
        const float* A_l   = Amat  + (size_t)l * DM * DS;
        const float* Dp_l  = Dp    + (size_t)l * DM;
        const float* nw_l  = norm_w + (size_t)l * DI;
        const unsigned short* Wi16_l  = Wi16  + (size_t)l * 2 * DM * DI;
        const unsigned short* Wo16_l  = Wo16  + (size_t)l * DI * DM;
        const unsigned short* W216_l  = W216  + (size_t)l * DM * DD;
        const unsigned short* Wcat16_l = Wcat16 + (size_t)l * NW * DM;

        rmsnorm_kernel<<<TT, DI / 4, 0, stream>>>(x, nw_l, h16);

        // proj16 = bf16(h @ Wi^T) : M=TT, N=2*DM, K=DI  (64x128 tiles, 1536 blocks)
        gemm_bf16<<<dim3(2 * DM / 128, TT / 64), 256, 0, stream>>>(
            h16, Wi16_l, nullptr, nullptr, (float*)proj16, TT, 2 * DM, DI, DI, DI, 2 * DM, 0, 1);

        conv_silu_kernel<<<TT, DM / 8, 0, stream>>>(proj16, cw_l, cb_l, aconv16);

        // BCD = aconv @ Wcat^T (Bm | Cm | dd1), split-K MFMA + reduce
        gemm_skinny_bf16<<<dim3(TT / 128, KS), 256, 0, stream>>>(aconv16, Wcat16_l, Part);
        skinny_reduce<<<TT * NW / 256, 256, 0, stream>>>(Part, BCD, dd16);

        // delta = softplus(Dp + dd1 @ W2^T) -> dtv (streaming, 1536 blocks)
        delta_kernel<<<dim3(DM / 256, TT / 16), 256, 0, stream>>>(dd16, W216_l, Dp_l, dtv);

        // chunk-parallel scan (thread-per-d)
        scan_pass1<<<dim3(DM / 256, NCH, BB), 256, 0, stream>>>(dtv, aconv16, BCD, A_l, PQ);
        scan_carry<<<BB * DM * DS / 256, 256, 0, stream>>>(PQ);
        scan_pass2<<<dim3(DM / 256, NCH, BB), 256, 0, stream>>>(
            dtv, aconv16, BCD, proj16, A_l, Dp_l, PQ, y16);

        // x = x + y @ Wo^T : M=TT, N=DI, K=DM  (64x128 tiles, 384 blocks)
        gemm_bf16<<<dim3(DI / 128, TT / 64), 256, 0, stream>>>(
            y16, Wo16_l, x, nullptr, x, TT, DI, DM, DM, DM, DI, 0, 0);
    }

    cls_kernel<<<TT, 64, 0, stream>>>(x, cls_w, cls_b, logits);
}

// Round 12
// 674.289 us; speedup vs baseline: 1.0790x; 1.0047x over previous
//
#include <hip/hip_runtime.h>
#include <hip/hip_bf16.h>
#include <math.h>

// Problem constants
#define NLAB 9
#define NL   2
#define DI   768
#define DM   1536
#define DS   16
#define KC   4
#define DD   96
#define BB   2
#define SS   2048
#define TT   (BB*SS)
#define EPSF 1e-6f

// chunked scan config
#define NCH  64
#define CL   (SS/NCH)   // 32

// skinny fused projection width: 16 (B) + 16 (C) + 96 (dd1)
#define NW   128
// split-K factor for the skinny GEMM (K=DM=1536 -> 8 x 192)
#define KS   8
#define KSL  (DM/KS)    // 192

typedef __attribute__((ext_vector_type(4))) float f32x4;
typedef __attribute__((ext_vector_type(8))) short bf16x8;
typedef __attribute__((ext_vector_type(4))) unsigned short us4;
typedef __attribute__((ext_vector_type(8))) unsigned short us8;

__device__ __forceinline__ float siluf(float x) { return x / (1.f + __expf(-x)); }
__device__ __forceinline__ float softplusf(float x) { return x > 15.f ? x : log1pf(__expf(x)); }

// f32 -> bf16 (RNE, finite inputs)
__device__ __forceinline__ unsigned short f2bf(float f) {
    unsigned u = __float_as_uint(f);
    return (unsigned short)((u + 0x7fffu + ((u >> 16) & 1u)) >> 16);
}
__device__ __forceinline__ float bf2f(unsigned short s) {
    return __uint_as_float((unsigned)s << 16);
}

// XCD-aware tile map: HW round-robins flat block id across 8 XCDs (flat&7).
// Square per-XCD regions so the working set fits the 4 MiB per-XCD L2.
__device__ __forceinline__ void xcd_map(int gx, int gy, int bx, int by,
                                        int& bmt, int& bnt)
{
    int flat = by * gx + bx;
    if ((gx & 1) == 0 && (gy & 3) == 0) {
        int halfx = gx >> 1, quarty = gy >> 2;
        int xcd = flat & 7, local = flat >> 3;
        bnt = (xcd & 1) * halfx + local % halfx;
        bmt = (xcd >> 1) * quarty + local / halfx;
    } else { bmt = by; bnt = bx; }
}

__global__ void f32_to_bf16(const float* __restrict__ src,
                            unsigned short* __restrict__ dst, int n)
{
    int i = (blockIdx.x * 256 + threadIdx.x) * 8;
    if (i >= n) return;
    float4 a = *(const float4*)(src + i);
    float4 b = *(const float4*)(src + i + 4);
    union { unsigned short s[8]; uint4 v; } o;
    o.s[0] = f2bf(a.x); o.s[1] = f2bf(a.y); o.s[2] = f2bf(a.z); o.s[3] = f2bf(a.w);
    o.s[4] = f2bf(b.x); o.s[5] = f2bf(b.y); o.s[6] = f2bf(b.z); o.s[7] = f2bf(b.w);
    *(uint4*)(dst + i) = o.v;
}

// x[t,:] = emb[ids[t],:] * mask[t]
__global__ void embed_kernel(const int* __restrict__ ids, const int* __restrict__ mask,
                             const float* __restrict__ emb, float* __restrict__ x)
{
    int t = blockIdx.x;
    int i = threadIdx.x;
    float m = (float)mask[t];
    int id = ids[t];
    float4 v = ((const float4*)(emb + (size_t)id * DI))[i];
    v.x *= m; v.y *= m; v.z *= m; v.w *= m;
    ((float4*)(x + (size_t)t * DI))[i] = v;
}

// h16[t,:] = bf16( x[t,:] * rsqrt(mean(x^2)+eps) * w )  — float4-vectorized (G13)
__global__ __launch_bounds__(192) void rmsnorm_kernel(
    const float* __restrict__ x, const float* __restrict__ w,
    unsigned short* __restrict__ h)
{
    __shared__ float red[3];
    int t = blockIdx.x;
    float4 v = ((const float4*)(x + (size_t)t * DI))[threadIdx.x];
    float ss = v.x * v.x + v.y * v.y + v.z * v.z + v.w * v.w;
    #pragma unroll
    for (int m = 1; m < 64; m <<= 1) ss += __shfl_xor(ss, m, 64);
    if ((threadIdx.x & 63) == 0) red[threadIdx.x >> 6] = ss;
    __syncthreads();
    float scale = rsqrtf((red[0] + red[1] + red[2]) * (1.f / DI) + EPSF);
    float4 wv = ((const float4*)w)[threadIdx.x];
    us4 o = { f2bf(v.x * scale * wv.x), f2bf(v.y * scale * wv.y),
              f2bf(v.z * scale * wv.z), f2bf(v.w * scale * wv.w) };
    *(us4*)(h + (size_t)t * DI + threadIdx.x * 4) = o;
}

// ---- 64x128 bf16 MFMA GEMM: 3-buffer pipeline, counted vmcnt ----
// 4 waves (2Mx2N), acc[2][4], LDS 36KB -> 4 blocks/CU; 2x grid vs 128^2:
// block-level concurrency hides the per-tile barrier drain (m114; round-11 -44us).
// Chunk-XOR LDS swizzle (both-sides involution; row bases multiples of 16).
#define STAGE_T64(AS, BS, KT) do {                                                            \
    {                                                                                         \
        int rbase = wave * 16;                                                                \
        int row = rbase + (lane >> 2);                                                        \
        int c8 = (((lane & 3) ^ ((lane >> 3) & 3)) * 8);                                      \
        __builtin_amdgcn_global_load_lds(                                                     \
            (const __attribute__((address_space(1))) unsigned int*)(Arow + (size_t)row * lda + (KT) + c8), \
            (__attribute__((address_space(3))) unsigned int*)((AS) + rbase * 32), 16, 0, 0);  \
    }                                                                                         \
    _Pragma("unroll")                                                                         \
    for (int it = 0; it < 2; ++it) {                                                          \
        int rbase = it * 64 + wave * 16;                                                      \
        int row = rbase + (lane >> 2);                                                        \
        int c8 = (((lane & 3) ^ ((lane >> 3) & 3)) * 8);                                      \
        __builtin_amdgcn_global_load_lds(                                                     \
            (const __attribute__((address_space(1))) unsigned int*)(Brow + (size_t)row * ldb + (KT) + c8), \
            (__attribute__((address_space(3))) unsigned int*)((BS) + rbase * 32), 16, 0, 0);  \
    } } while (0)

#define COMPUTE_T64(AS, BS) do {                                                              \
    bf16x8 af[2], bfr[4];                                                                     \
    const int khs = (kh ^ ((lr >> 1) & 3)) * 8;                                               \
    _Pragma("unroll")                                                                         \
    for (int i = 0; i < 2; ++i)                                                               \
        af[i] = *(const bf16x8*)&(AS)[(wm + i * 16 + lr) * 32 + khs];                         \
    _Pragma("unroll")                                                                         \
    for (int j = 0; j < 4; ++j)                                                               \
        bfr[j] = *(const bf16x8*)&(BS)[(wn + j * 16 + lr) * 32 + khs];                        \
    _Pragma("unroll")                                                                         \
    for (int i = 0; i < 2; ++i)                                                               \
        _Pragma("unroll")                                                                     \
        for (int j = 0; j < 4; ++j)                                                           \
            acc[i][j] = __builtin_amdgcn_mfma_f32_16x16x32_bf16(af[i], bfr[j], acc[i][j], 0, 0, 0); \
    } while (0)

#define WAIT_BAR3(T, NT) do {                                                                 \
    if ((T) + 1 < (NT)) asm volatile("s_waitcnt vmcnt(3)" ::: "memory");                      \
    else                asm volatile("s_waitcnt vmcnt(0)" ::: "memory");                      \
    __builtin_amdgcn_s_barrier();                                                             \
} while (0)

// out16: when 1, C is written as bf16 (ushort*), act/bias/Rres still applied in f32.
__global__ __launch_bounds__(256) void gemm_bf16(
    const unsigned short* __restrict__ A, const unsigned short* __restrict__ B,
    const float* __restrict__ Rres, const float* __restrict__ bias,
    float* __restrict__ C, int M, int N, int K,
    int lda, int ldb, int ldc, int act, int out16)
{
    __shared__ unsigned short As0[64 * 32];
    __shared__ unsigned short Bs0[128 * 32];
    __shared__ unsigned short As1[64 * 32];
    __shared__ unsigned short Bs1[128 * 32];
    __shared__ unsigned short As2[64 * 32];
    __shared__ unsigned short Bs2[128 * 32];
    const int tid = threadIdx.x;
    const int wave = tid >> 6, lane = tid & 63;

    int bmt, bnt;
    xcd_map(gridDim.x, gridDim.y, blockIdx.x, blockIdx.y, bmt, bnt);
    const int bm = bmt * 64, bn = bnt * 128;

    const int wm = (wave >> 1) * 32, wn = (wave & 1) * 64;
    const int lr = lane & 15, kh = lane >> 4;

    f32x4 acc[2][4] = {};

    const unsigned short* Arow = A + (size_t)bm * lda;
    const unsigned short* Brow = B + (size_t)bn * ldb;

    const int nt = K >> 5;
    STAGE_T64(As0, Bs0, 0);
    STAGE_T64(As1, Bs1, 32);

    int t = 0;
    while (true) {
        WAIT_BAR3(t, nt);
        if (t + 2 < nt) STAGE_T64(As2, Bs2, (t + 2) * 32);
        COMPUTE_T64(As0, Bs0);
        if (++t == nt) break;
        WAIT_BAR3(t, nt);
        if (t + 2 < nt) STAGE_T64(As0, Bs0, (t + 2) * 32);
        COMPUTE_T64(As1, Bs1);
        if (++t == nt) break;
        WAIT_BAR3(t, nt);
        if (t + 2 < nt) STAGE_T64(As1, Bs1, (t + 2) * 32);
        COMPUTE_T64(As2, Bs2);
        if (++t == nt) break;
    }

    #pragma unroll
    for (int i = 0; i < 2; ++i) {
        #pragma unroll
        for (int j = 0; j < 4; ++j) {
            #pragma unroll
            for (int r = 0; r < 4; ++r) {
                int row = bm + wm + i * 16 + kh * 4 + r;
                int col = bn + wn + j * 16 + lr;
                float v = acc[i][j][r];
                if (bias) v += bias[col];
                if (act == 1) v = softplusf(v);
                if (Rres) v += Rres[(size_t)row * ldc + col];
                if (out16)
                    ((unsigned short*)C)[(size_t)row * ldc + col] = f2bf(v);
                else
                    C[(size_t)row * ldc + col] = v;
            }
        }
    }
}

// ---- split-K skinny GEMM, 64x128 tiles (2 blocks/CU vs 1 at 128^2) ----
// Part[ks] = aconv16[bm:bm+64, ks*192:(ks+1)*192] @ Wcat16^T; grid 64x8=512.
__global__ __launch_bounds__(256) void gemm_skinny_bf16(
    const unsigned short* __restrict__ A, const unsigned short* __restrict__ B,
    float* __restrict__ Part)
{
    __shared__ unsigned short As0[64 * 32];
    __shared__ unsigned short Bs0[128 * 32];
    __shared__ unsigned short As1[64 * 32];
    __shared__ unsigned short Bs1[128 * 32];
    __shared__ unsigned short As2[64 * 32];
    __shared__ unsigned short Bs2[128 * 32];
    const int tid = threadIdx.x;
    const int wave = tid >> 6, lane = tid & 63;
    const int bm = blockIdx.x * 64;
    const int ks = blockIdx.y;
    const int k0 = ks * KSL;
    const int wm = (wave >> 1) * 32, wn = (wave & 1) * 64;
    const int lr = lane & 15, kh = lane >> 4;
    const int lda = DM, ldb = DM;

    f32x4 acc[2][4] = {};

    const unsigned short* Arow = A + (size_t)bm * DM;
    const unsigned short* Brow = B;   // 128 x DM

    const int nt = KSL >> 5;   // 6
    STAGE_T64(As0, Bs0, k0);
    STAGE_T64(As1, Bs1, k0 + 32);

    int t = 0;
    while (true) {
        WAIT_BAR3(t, nt);
        if (t + 2 < nt) STAGE_T64(As2, Bs2, k0 + (t + 2) * 32);
        COMPUTE_T64(As0, Bs0);
        if (++t == nt) break;
        WAIT_BAR3(t, nt);
        if (t + 2 < nt) STAGE_T64(As0, Bs0, k0 + (t + 2) * 32);
        COMPUTE_T64(As1, Bs1);
        if (++t == nt) break;
        WAIT_BAR3(t, nt);
        if (t + 2 < nt) STAGE_T64(As1, Bs1, k0 + (t + 2) * 32);
        COMPUTE_T64(As2, Bs2);
        if (++t == nt) break;
    }

    float* out = Part + (size_t)ks * TT * NW;
    #pragma unroll
    for (int i = 0; i < 2; ++i) {
        #pragma unroll
        for (int j = 0; j < 4; ++j) {
            #pragma unroll
            for (int r = 0; r < 4; ++r) {
                int row = bm + wm + i * 16 + kh * 4 + r;
                int col = wn + j * 16 + lr;
                out[(size_t)row * NW + col] = acc[i][j][r];
            }
        }
    }
}

// sum KS partials; cols 0..31 -> BCD f32 (scans); cols 32..127 -> dd16 bf16 only.
__global__ void skinny_reduce(const float* __restrict__ Part,
                              float* __restrict__ BCD, unsigned short* __restrict__ dd16)
{
    int idx = blockIdx.x * 256 + threadIdx.x;     // over TT*NW
    float s = 0.f;
    #pragma unroll
    for (int ks = 0; ks < KS; ++ks)
        s += Part[(size_t)ks * TT * NW + idx];
    int col = idx & (NW - 1);
    if (col < 32) BCD[idx] = s;
    else          dd16[(size_t)(idx >> 7) * DD + (col - 32)] = f2bf(s);
}

// delta[t][d] = softplus(Dp[d] + dot96(dd1[t,:], W2[d,:])) -> dtv f32.
// Streaming: grid (DM/256, TT/16) = 1536 blocks (6/CU); dd1 tile in LDS,
// wave-uniform us8 broadcasts; W2 row in 96 f32 regs (no spill).
__global__ __launch_bounds__(256) void delta_kernel(
    const unsigned short* __restrict__ dd16, const unsigned short* __restrict__ W2,
    const float* __restrict__ Dp, float* __restrict__ dtv)
{
    __shared__ unsigned short sdd[16 * DD];   // [tt][k], 3 KB
    const int d = blockIdx.x * 256 + threadIdx.x;
    const int t0 = blockIdx.y * 16;

    for (int i = threadIdx.x; i < 16 * DD; i += 256)
        sdd[i] = dd16[(size_t)t0 * DD + i];

    float w[DD];
    {
        const uint4* wp = (const uint4*)(W2 + (size_t)d * DD);
        #pragma unroll
        for (int i = 0; i < DD / 8; ++i) {
            uint4 v = wp[i];
            const unsigned short* ps = (const unsigned short*)&v;
            #pragma unroll
            for (int e = 0; e < 8; ++e) w[i * 8 + e] = bf2f(ps[e]);
        }
    }
    float dpd = Dp[d];
    __syncthreads();

    for (int tt = 0; tt < 16; ++tt) {
        float acc = dpd;
        #pragma unroll
        for (int kk = 0; kk < DD / 8; ++kk) {
            us8 dv = *(const us8*)&sdd[tt * DD + kk * 8];   // wave-uniform broadcast
            #pragma unroll
            for (int e = 0; e < 8; ++e)
                acc += bf2f(dv[e]) * w[kk * 8 + e];
        }
        dtv[(size_t)(t0 + tt) * DM + d] = softplusf(acc);
    }
}

// causal depthwise conv (K=4) + silu -> aconv16 (bf16). Vectorized x8.
__global__ __launch_bounds__(192) void conv_silu_kernel(
    const unsigned short* __restrict__ proj16, const float* __restrict__ cw,
    const float* __restrict__ cb, unsigned short* __restrict__ aconv16)
{
    int t = blockIdx.x;
    int d0 = threadIdx.x * 8;
    int p = t & (SS - 1);

    float4 w[8];
    #pragma unroll
    for (int k = 0; k < 8; ++k) w[k] = ((const float4*)cw)[d0 + k];  // taps 0..3 for d0+k
    float acc[8];
    #pragma unroll
    for (int k = 0; k < 8; ++k) acc[k] = cb[d0 + k];

    #pragma unroll
    for (int j = 0; j < KC; ++j) {
        int pp = p - (KC - 1) + j;
        if (pp >= 0) {
            const unsigned short* rowp = proj16 + (size_t)(t - (KC - 1) + j) * (2 * DM) + d0;
            us4 lo = *(const us4*)rowp;
            us4 hi = *(const us4*)(rowp + 4);
            #pragma unroll
            for (int k = 0; k < 4; ++k) {
                acc[k]     += (&w[k].x)[j]     * bf2f(lo[k]);
                acc[4 + k] += (&w[4 + k].x)[j] * bf2f(hi[k]);
            }
        }
    }
    union { unsigned short s[8]; uint4 v; } o;
    #pragma unroll
    for (int k = 0; k < 8; ++k) o.s[k] = f2bf(siluf(acc[k]));
    *(uint4*)(aconv16 + (size_t)t * DM + d0) = o.v;
}

// pack [WB;WC;W1] -> Wcat16[l][128][DM] (bf16)
__global__ void concat_w_kernel(const float* __restrict__ WB, const float* __restrict__ WC,
                                const float* __restrict__ W1, unsigned short* __restrict__ Wcat16)
{
    int l = blockIdx.y;
    int row = blockIdx.x;
    const float* src;
    if (row < 16)      src = WB + (size_t)l * DS * DM + (size_t)row * DM;
    else if (row < 32) src = WC + (size_t)l * DS * DM + (size_t)(row - 16) * DM;
    else               src = W1 + (size_t)l * DD * DM + (size_t)(row - 32) * DM;
    unsigned short* dst = Wcat16 + ((size_t)l * NW + row) * DM;
    for (int i = threadIdx.x; i < DM / 4; i += 256) {
        float4 v = ((const float4*)src)[i];
        us4 u = { f2bf(v.x), f2bf(v.y), f2bf(v.z), f2bf(v.w) };
        *(us4*)(dst + i * 4) = u;
    }
}

// ---- chunk-parallel selective scan: thread-per-d, s-states in registers ----
__global__ __launch_bounds__(256) void scan_pass1(
    const float* __restrict__ dtv, const unsigned short* __restrict__ av16,
    const float* __restrict__ BCD, const float* __restrict__ Amat,
    float2* __restrict__ PQ)
{
    __shared__ float4 sB4[CL][DS / 4];
    int b = blockIdx.z, c = blockIdx.y;
    int d = blockIdx.x * 256 + threadIdx.x;
    size_t rowbase = (size_t)b * SS + (size_t)c * CL;

    for (int i = threadIdx.x; i < CL * DS; i += 256)
        ((float*)sB4)[i] = BCD[(rowbase + (i >> 4)) * NW + (i & 15)];
    __syncthreads();

    float negA[DS], hid[DS];
    #pragma unroll
    for (int s = 0; s < DS; ++s) {
        negA[s] = -Amat[(size_t)d * DS + s];
        hid[s] = 0.f;
    }
    float cum = 0.f;

    const float* pd = dtv + rowbase * DM + d;
    const unsigned short* pa = av16 + rowbase * DM + d;
    for (int t = 0; t < CL; ++t) {
        float dt = pd[(size_t)t * DM];
        float avv = bf2f(pa[(size_t)t * DM]);
        cum += dt;
        float xv = dt * avv;
        #pragma unroll
        for (int j = 0; j < DS / 4; ++j) {
            float4 bv = sB4[t][j];
            hid[4*j+0] = __expf(dt * negA[4*j+0]) * hid[4*j+0] + xv * bv.x;
            hid[4*j+1] = __expf(dt * negA[4*j+1]) * hid[4*j+1] + xv * bv.y;
            hid[4*j+2] = __expf(dt * negA[4*j+2]) * hid[4*j+2] + xv * bv.z;
            hid[4*j+3] = __expf(dt * negA[4*j+3]) * hid[4*j+3] + xv * bv.w;
        }
    }
    float2* out = PQ + ((size_t)(b * NCH + c) * DM + d) * DS;
    #pragma unroll
    for (int s = 0; s < DS; ++s)
        out[s] = make_float2(__expf(cum * negA[s]), hid[s]);
}

// 49152 chains, NCH sequential chunk steps each; rewrites .x = carry-in.
// Batched prefetch: 8 independent loads then 8 dependent FMAs.
__global__ void scan_carry(float2* __restrict__ PQ)
{
    int idx = blockIdx.x * 256 + threadIdx.x;
    int b = idx / (DM * DS);
    int r = idx - b * (DM * DS);
    float2* base = PQ + (size_t)b * NCH * (DM * DS) + r;
    float carry = 0.f;
    for (int cb = 0; cb < NCH; cb += 8) {
        float2 v[8];
        #pragma unroll
        for (int j = 0; j < 8; ++j)
            v[j] = base[(size_t)(cb + j) * (DM * DS)];
        #pragma unroll
        for (int j = 0; j < 8; ++j) {
            base[(size_t)(cb + j) * (DM * DS)].x = carry;
            carry = v[j].x * carry + v[j].y;
        }
    }
}

// pass2: re-run seeded with carry; y16 = bf16((hid·Cm + Dp*av) * silu(gate))
__global__ __launch_bounds__(256) void scan_pass2(
    const float* __restrict__ dtv, const unsigned short* __restrict__ av16,
    const float* __restrict__ BCD,
    const unsigned short* __restrict__ proj16, const float* __restrict__ Amat,
    const float* __restrict__ Dp, const float2* __restrict__ PQ,
    unsigned short* __restrict__ y)
{
    __shared__ float4 sB4[CL][DS / 4];
    __shared__ float4 sC4[CL][DS / 4];
    int b = blockIdx.z, c = blockIdx.y;
    int d = blockIdx.x * 256 + threadIdx.x;
    size_t rowbase = (size_t)b * SS + (size_t)c * CL;

    for (int i = threadIdx.x; i < CL * DS; i += 256) {
        size_t row = rowbase + (i >> 4);
        ((float*)sB4)[i] = BCD[row * NW + (i & 15)];
        ((float*)sC4)[i] = BCD[row * NW + 16 + (i & 15)];
    }
    __syncthreads();

    float negA[DS], hid[DS];
    const float2* pin = PQ + ((size_t)(b * NCH + c) * DM + d) * DS;
    #pragma unroll
    for (int s = 0; s < DS; ++s) {
        negA[s] = -Amat[(size_t)d * DS + s];
        hid[s] = pin[s].x;            // carry-in
    }
    float Dpd = Dp[d];

    const float* pd = dtv + rowbase * DM + d;
    const unsigned short* pa = av16 + rowbase * DM + d;
    const unsigned short* gp = proj16 + rowbase * (2 * DM) + DM + d;
    unsigned short* yp = y + rowbase * DM + d;

    for (int t = 0; t < CL; ++t) {
        float dt = pd[(size_t)t * DM];
        float avv = bf2f(pa[(size_t)t * DM]);
        float g  = bf2f(gp[(size_t)t * (2 * DM)]);
        float xv = dt * avv;
        float acc0 = 0.f, acc1 = 0.f, acc2 = 0.f, acc3 = 0.f;
        #pragma unroll
        for (int j = 0; j < DS / 4; ++j) {
            float4 bv = sB4[t][j];
            float4 cv = sC4[t][j];
            hid[4*j+0] = __expf(dt * negA[4*j+0]) * hid[4*j+0] + xv * bv.x;
            hid[4*j+1] = __expf(dt * negA[4*j+1]) * hid[4*j+1] + xv * bv.y;
            hid[4*j+2] = __expf(dt * negA[4*j+2]) * hid[4*j+2] + xv * bv.z;
            hid[4*j+3] = __expf(dt * negA[4*j+3]) * hid[4*j+3] + xv * bv.w;
            acc0 += hid[4*j+0] * cv.x;
            acc1 += hid[4*j+1] * cv.y;
            acc2 += hid[4*j+2] * cv.z;
            acc3 += hid[4*j+3] * cv.w;
        }
        float contrib = (acc0 + acc1) + (acc2 + acc3);
        yp[(size_t)t * DM] = f2bf((contrib + Dpd * avv) * siluf(g));
    }
}

// logits: wave-per-token, 4 tokens per block
__global__ __launch_bounds__(256) void cls_kernel(
    const float* __restrict__ x, const float* __restrict__ W,
    const float* __restrict__ bias, float* __restrict__ out)
{
    int t = blockIdx.x * 4 + (threadIdx.x >> 6);
    int lane = threadIdx.x & 63;
    const float* xr = x + (size_t)t * DI;
    float acc[NLAB];
    #pragma unroll
    for (int n = 0; n < NLAB; ++n) acc[n] = 0.f;
    for (int i = lane; i < DI; i += 64) {
        float xv = xr[i];
        #pragma unroll
        for (int n = 0; n < NLAB; ++n) acc[n] += xv * W[(size_t)n * DI + i];
    }
    #pragma unroll
    for (int n = 0; n < NLAB; ++n)
        #pragma unroll
        for (int m = 1; m < 64; m <<= 1) acc[n] += __shfl_xor(acc[n], m, 64);
    if (lane < NLAB) out[(size_t)t * NLAB + lane] = acc[lane] + bias[lane];
}

extern "C" void kernel_launch(void* const* d_in, const int* in_sizes, int n_in,
                              void* d_out, int out_size, void* d_ws, size_t ws_size,
                              hipStream_t stream)
{
    const int*   ids    = (const int*)d_in[0];
    const int*   mask   = (const int*)d_in[1];
    const float* emb    = (const float*)d_in[2];
    const float* norm_w = (const float*)d_in[3];
    const float* Wi     = (const float*)d_in[4];
    const float* conv_w = (const float*)d_in[5];
    const float* conv_b = (const float*)d_in[6];
    const float* sB_w   = (const float*)d_in[7];
    const float* sC_w   = (const float*)d_in[8];
    const float* sD1_w  = (const float*)d_in[9];
    const float* sD2_w  = (const float*)d_in[10];
    const float* Amat   = (const float*)d_in[11];
    const float* Dp     = (const float*)d_in[12];
    const float* out_w  = (const float*)d_in[13];
    const float* cls_w  = (const float*)d_in[14];
    const float* cls_b  = (const float*)d_in[15];
    float* logits = (float*)d_out;

    // workspace layout (float units)
    float* ws = (float*)d_ws;
    size_t off = 0;
    float* x     = ws + off; off += (size_t)TT * DI;
    unsigned short* proj16 = (unsigned short*)(ws + off); off += (size_t)TT * 2 * DM / 2;  // bf16 [a|gate]
    float* dtv   = ws + off; off += (size_t)TT * DM;   // softplus'd delta (planar f32)
    float* BCD   = ws + off; off += (size_t)TT * NW;
    // Part (KS*TT*NW = 4.2M fl) and PQ (BB*NCH*DM*DS*2 = 6.3M fl) are liveness-disjoint: share.
    size_t scratch_sz = (size_t)BB * NCH * DM * DS * 2;
    size_t part_sz = (size_t)KS * TT * NW;
    if (part_sz > scratch_sz) scratch_sz = part_sz;
    float* Part  = ws + off;
    float2* PQ   = (float2*)(ws + off); off += scratch_sz;
    unsigned short* y16     = (unsigned short*)(ws + off); off += (size_t)TT * DM / 2;
    unsigned short* aconv16 = (unsigned short*)(ws + off); off += (size_t)TT * DM / 2;
    unsigned short* Wi16    = (unsigned short*)(ws + off); off += (size_t)NL * 2 * DM * DI / 2;
    unsigned short* Wo16    = (unsigned short*)(ws + off); off += (size_t)NL * DI * DM / 2;
    unsigned short* W216    = (unsigned short*)(ws + off); off += (size_t)NL * DM * DD / 2;
    unsigned short* dd16    = (unsigned short*)(ws + off); off += (size_t)TT * DD / 2;
    unsigned short* Wcat16  = (unsigned short*)(ws + off); off += (size_t)NL * NW * DM / 2;
    if (ws_size < off * sizeof(float)) return;  // fail loud

    // h16 overlays dtv: h16 is dead after in_proj GEMM; dtv written only after that
    // (delta_kernel).
    unsigned short* h16 = (unsigned short*)dtv;

    embed_kernel<<<TT, DI / 4, 0, stream>>>(ids, mask, emb, x);
    concat_w_kernel<<<dim3(NW, NL), 256, 0, stream>>>(sB_w, sC_w, sD1_w, Wcat16);

    // whole-tensor weight conversions (all layers at once)
    f32_to_bf16<<<(NL * 2 * DM * DI / 8 + 255) / 256, 256, 0, stream>>>(Wi, Wi16, NL * 2 * DM * DI);
    f32_to_bf16<<<(NL * DI * DM / 8 + 255) / 256, 256, 0, stream>>>(out_w, Wo16, NL * DI * DM);
    f32_to_bf16<<<(NL * DM * DD / 8 + 255) / 256, 256, 0, stream>>>(sD2_w, W216, NL * DM * DD);

    for (int l = 0; l < NL; ++l) {
        const float* cw_l  = conv_w + (size_t)l * DM * KC;
        const float* cb_l  = conv_b + (size_t)l * DM;
        const float* A_l   = Amat  + (size_t)l * DM * DS;
        const float* Dp_l  = Dp    + (size_t)l * DM;
        const float* nw_l  = norm_w + (size_t)l * DI;
        const unsigned short* Wi16_l  = Wi16  + (size_t)l * 2 * DM * DI;
        const unsigned short* Wo16_l  = Wo16  + (size_t)l * DI * DM;
        const unsigned short* W216_l  = W216  + (size_t)l * DM * DD;
        const unsigned short* Wcat16_l = Wcat16 + (size_t)l * NW * DM;

        rmsnorm_kernel<<<TT, DI / 4, 0, stream>>>(x, nw_l, h16);

        // proj16 = bf16(h @ Wi^T) : M=TT, N=2*DM, K=DI  (64x128 tiles, 1536 blocks)
        gemm_bf16<<<dim3(2 * DM / 128, TT / 64), 256, 0, stream>>>(
            h16, Wi16_l, nullptr, nullptr, (float*)proj16, TT, 2 * DM, DI, DI, DI, 2 * DM, 0, 1);

        conv_silu_kernel<<<TT, DM / 8, 0, stream>>>(proj16, cw_l, cb_l, aconv16);

        // BCD = aconv @ Wcat^T (Bm | Cm | dd1), split-K MFMA (64x128, 512 blocks) + reduce
        gemm_skinny_bf16<<<dim3(TT / 64, KS), 256, 0, stream>>>(aconv16, Wcat16_l, Part);
        skinny_reduce<<<TT * NW / 256, 256, 0, stream>>>(Part, BCD, dd16);

        // delta = softplus(Dp + dd1 @ W2^T) -> dtv (streaming, 1536 blocks)
        delta_kernel<<<dim3(DM / 256, TT / 16), 256, 0, stream>>>(dd16, W216_l, Dp_l, dtv);

        // chunk-parallel scan (thread-per-d)
        scan_pass1<<<dim3(DM / 256, NCH, BB), 256, 0, stream>>>(dtv, aconv16, BCD, A_l, PQ);
        scan_carry<<<BB * DM * DS / 256, 256, 0, stream>>>(PQ);
        scan_pass2<<<dim3(DM / 256, NCH, BB), 256, 0, stream>>>(
            dtv, aconv16, BCD, proj16, A_l, Dp_l, PQ, y16);

        // x = x + y @ Wo^T : M=TT, N=DI, K=DM  (64x128 tiles, 384 blocks)
        gemm_bf16<<<dim3(DI / 128, TT / 64), 256, 0, stream>>>(
            y16, Wo16_l, x, nullptr, x, TT, DI, DM, DM, DM, DI, 0, 0);
    }

    cls_kernel<<<TT / 4, 256, 0, stream>>>(x, cls_w, cls_b, logits);
}